// Round 1
// baseline (123.911 us; speedup 1.0000x reference)
//
#include <hip/hip_runtime.h>
#include <math.h>

// SSIM loss, fused separable implementation.
// Inputs: Ii, Ir f32 [32,3,512,512]; window f32 [3,1,11,11] (Gaussian outer product).
// Output: scalar f32 = 1 - mean(ssim_map).
//
// Key algebra: with s=x+y, d=x-y and G = gaussian conv,
//   mp=G(s)=mu1+mu2, mm=G(d)=mu1-mu2,
//   varP=G(s^2)-mp^2 = s11+s22+2*s12, varM=G(d^2)-mm^2 = s11+s22-2*s12.
//   2*mu1mu2 = (mp^2-mm^2)/2 ; mu1^2+mu2^2 = (mp^2+mm^2)/2
//   2*s12    = (varP-varM)/2 ; s11+s22    = (varP+varM)/2
// -> only 4 separable convolutions.

#define HH 512
#define WW 512
#define NPLANES 96   // 32*3
#define STRIPS 8
#define ROWS 64      // output rows per block
#define CH 8         // chunk rows per barrier period
#define NQ 4         // quantities: s, d, s^2, d^2
#define NT 512

#define C1F 0.0001f  // 0.01^2
#define C2F 0.0009f  // 0.03^2

__device__ __forceinline__ int swz(int c) { return c ^ ((c >> 5) & 31); }

extern "C" __global__ __launch_bounds__(NT, 2)
void ssim_main(const float* __restrict__ Ii, const float* __restrict__ Ir,
               const float* __restrict__ win, float* __restrict__ partial) {
  __shared__ float vbuf[CH * NQ * WW];   // [row][q][col'] 64 KB

  const int tid = threadIdx.x;
  const int b = blockIdx.x;
  const int plane = b >> 3;
  const int strip = b & 7;
  const int r0 = strip * ROWS;           // r0 % 16 == 0 (needed for static ring phases)

  // Derive 1-D gaussian from the 2-D window: w2d[i][j] = g_i*g_j
  // g_j = w2d[5][j] / sqrt(w2d[5][5])   (uniform -> scalar regs)
  float g[11];
  {
    float ginv = 1.0f / sqrtf(win[5 * 11 + 5]);
#pragma unroll
    for (int j = 0; j < 11; ++j) g[j] = win[55 + j] * ginv;
  }

  const size_t pbase = (size_t)plane * (HH * WW);
  const float* pA = Ii + pbase + tid;    // this thread's column
  const float* pB = Ir + pbase + tid;
  const int wcol = swz(tid);             // swizzled column for LDS writes

  // ring accumulators (mod-16), 4 quantities; all indices become compile-time
  float rS[16], rD[16], rP[16], rM[16];

  float sum = 0.f;

  // One vertical row step. rbase runtime, i/ph/lr compile-time (unrolled callers).
  // ph == (row - r0) mod 16 for row = rbase + i.
  auto vrow = [&](int rbase, int i, int ph, int lr) {
    const int r = rbase + i;
    float a = 0.f, bb = 0.f;
    if ((unsigned)r < (unsigned)HH) {    // uniform branch (zero padding rows)
      a = pA[(size_t)r * WW];
      bb = pB[(size_t)r * WW];
    }
    const float s = a + bb, d = a - bb;
    const float ss = s * s, dd = d * d;
    {
      const int sl = (ph + 5) & 15;      // start output o = row+5 (first tap, g[0])
      rS[sl] = g[0] * s; rD[sl] = g[0] * d; rP[sl] = g[0] * ss; rM[sl] = g[0] * dd;
    }
#pragma unroll
    for (int dd2 = 4; dd2 >= -5; --dd2) {
      const int sl = (ph + dd2 + 16) & 15;
      const float w = g[5 - dd2];
      rS[sl] += w * s; rD[sl] += w * d; rP[sl] += w * ss; rM[sl] += w * dd;
    }
    if (lr >= 0) {                       // output row (row-5) complete -> LDS
      const int sl = (ph + 11) & 15;
      const int base = lr * (NQ * WW) + wcol;
      vbuf[base         ] = rS[sl];
      vbuf[base +     WW] = rD[sl];
      vbuf[base + 2 * WW] = rP[sl];
      vbuf[base + 3 * WW] = rM[sl];
    }
  };

  // Horizontal conv + SSIM for the CH rows currently in LDS.
  auto horiz = [&]() {
    float h0[8], h1[8], h2[8], h3[8];
    const int rbase = (tid >> 6) * (NQ * WW);  // wave-uniform row
    const int c0 = (tid & 63) * 8;             // 8 output cols per thread
#pragma unroll
    for (int j = 0; j < 18; ++j) {
      const int col = c0 + j - 5;
      const int cc = min(max(col, 0), WW - 1);
      const int ad = rbase + swz(cc);
      const bool ok = (unsigned)col < (unsigned)WW;
      float v0 = vbuf[ad];
      float v1 = vbuf[ad + WW];
      float v2 = vbuf[ad + 2 * WW];
      float v3 = vbuf[ad + 3 * WW];
      v0 = ok ? v0 : 0.f; v1 = ok ? v1 : 0.f;
      v2 = ok ? v2 : 0.f; v3 = ok ? v3 : 0.f;
      const int clo = (j - 10 > 0) ? (j - 10) : 0;
      const int chi = (j < 7) ? j : 7;
#pragma unroll
      for (int c = clo; c <= chi; ++c) {
        const float w = g[j - c];
        if (c == j) { h0[c] = w * v0; h1[c] = w * v1; h2[c] = w * v2; h3[c] = w * v3; }
        else        { h0[c] += w * v0; h1[c] += w * v1; h2[c] += w * v2; h3[c] += w * v3; }
      }
    }
#pragma unroll
    for (int c = 0; c < 8; ++c) {
      const float mp = h0[c], mm = h1[c];
      const float mp2 = mp * mp, mm2 = mm * mm;
      const float varP = h2[c] - mp2;
      const float varM = h3[c] - mm2;
      const float num1 = 0.5f * (mp2 - mm2) + C1F;   // 2*mu1mu2 + C1
      const float den1 = 0.5f * (mp2 + mm2) + C1F;   // mu1^2+mu2^2 + C1
      const float num2 = 0.5f * (varP - varM) + C2F; // 2*s12 + C2
      const float den2 = 0.5f * (varP + varM) + C2F; // s11+s22 + C2
      sum += __fdividef(num1 * num2, den1 * den2);
    }
  };

  // Prologue: input rows r0-5 .. r0+4, no emission (fills the ring).
#pragma unroll
  for (int i = 0; i < 10; ++i) vrow(r0 - 5, i, (11 + i) & 15, -1);

  // 8 chunks of 8 rows as 4 x (A,B) so ring phases are static (period 16).
  for (int jj = 0; jj < 4; ++jj) {
    const int rbA = r0 + 5 + 16 * jj;
#pragma unroll
    for (int i = 0; i < 8; ++i) vrow(rbA, i, (5 + i) & 15, i);
    __syncthreads();
    horiz();
    __syncthreads();
    const int rbB = rbA + 8;
#pragma unroll
    for (int i = 0; i < 8; ++i) vrow(rbB, i, (13 + i) & 15, i);
    __syncthreads();
    horiz();
    __syncthreads();
  }

  // Block reduction (deterministic): wave shuffle -> LDS -> thread 0.
#pragma unroll
  for (int off = 32; off > 0; off >>= 1) sum += __shfl_down(sum, off, 64);
  if ((tid & 63) == 0) vbuf[tid >> 6] = sum;
  __syncthreads();
  if (tid == 0) {
    float t = 0.f;
#pragma unroll
    for (int wv = 0; wv < 8; ++wv) t += vbuf[wv];
    partial[b] = t;
  }
}

extern "C" __global__ void ssim_reduce(const float* __restrict__ partial,
                                       float* __restrict__ out, int n, float scale) {
  __shared__ float sm[4];
  const int tid = threadIdx.x;
  float v = 0.f;
  for (int i = tid; i < n; i += 256) v += partial[i];
#pragma unroll
  for (int off = 32; off > 0; off >>= 1) v += __shfl_down(v, off, 64);
  if ((tid & 63) == 0) sm[tid >> 6] = v;
  __syncthreads();
  if (tid == 0) {
    const float t = sm[0] + sm[1] + sm[2] + sm[3];
    out[0] = 1.0f - t * scale;
  }
}

extern "C" void kernel_launch(void* const* d_in, const int* in_sizes, int n_in,
                              void* d_out, int out_size, void* d_ws, size_t ws_size,
                              hipStream_t stream) {
  const float* Ii = (const float*)d_in[0];
  const float* Ir = (const float*)d_in[1];
  const float* win = (const float*)d_in[2];
  float* out = (float*)d_out;
  float* partial = (float*)d_ws;   // 768 floats

  const int nblocks = NPLANES * STRIPS;  // 768
  ssim_main<<<dim3(nblocks), dim3(NT), 0, stream>>>(Ii, Ir, win, partial);
  ssim_reduce<<<dim3(1), dim3(256), 0, stream>>>(partial, out, nblocks,
                                                 1.0f / 25165824.0f);
}